// Round 9
// baseline (383.557 us; speedup 1.0000x reference)
//
#include <hip/hip_runtime.h>
#include <hip/hip_bf16.h>
#include <stdint.h>

typedef float f32x4 __attribute__((ext_vector_type(4)));
typedef _Float16 half8 __attribute__((ext_vector_type(8)));

#define B_ 4096
#define T_ 256
#define D_ 18
#define H_ 32
#define GK 8192   // T_*H_
#define GN 512
#define SLOT 520  // hist ring slot stride in halves (16*32 + 8 pad)

#define K1_ 1.442695041f
#define K2_ 2.885390082f
#define X2_ __builtin_amdgcn_exp2f
#define RCP_ __builtin_amdgcn_rcpf

// Barrier draining ONLY LDS (lgkmcnt) — global loads/stores stay in flight.
__device__ __forceinline__ void ldsbar() {
  asm volatile("s_waitcnt lgkmcnt(0)\n\ts_barrier" ::: "memory");
}

// ---------- kernel 1: W1 fp32 -> fp16 (RNE) ----------
__global__ __launch_bounds__(256) void cvtw1_kernel(const float* __restrict__ w1,
                                                    unsigned short* __restrict__ dst) {
  int i = blockIdx.x * 256 + threadIdx.x;  // float4 index, total 1048576
  float4 v = ((const float4*)w1)[i];
  unsigned short a = __builtin_bit_cast(unsigned short, (_Float16)v.x);
  unsigned short b = __builtin_bit_cast(unsigned short, (_Float16)v.y);
  unsigned short c = __builtin_bit_cast(unsigned short, (_Float16)v.z);
  unsigned short d = __builtin_bit_cast(unsigned short, (_Float16)v.w);
  uint2 o; o.x = (unsigned)a | ((unsigned)b << 16); o.y = (unsigned)c | ((unsigned)d << 16);
  ((uint2*)dst)[i] = o;
}

// ---------- kernel 2: FUSED LSTM + GEMM + head ----------
// R15: R3-proven 8-wave LSTM structure (do not touch), with the [16 x 512]
// GEMM vs W1 folded into the per-step idle issue slots:
//  * gemm K = time. Window blk-1's h lives in ring parity po, stable all of
//    window blk (same hazard rule as the old flush). Per step tt: 4 MFMAs
//    gacc[nt] += W1frag(nt) x h-frag(po slot tt), per wave (wave w owns
//    n_out in [w*64, w*64+64)).
//  * W1 fragments register-prefetched one step ahead (wfA/wfB named sets;
//    static addresses, L2-resident chunks shared by all blocks on an XCD).
//  * epilogue: window 31's 8 slots, then relu(gacc+b1)*W2 + shuffle/LDS
//    reduce -> out. hs / part buffers and gemm/head kernels DELETED.
__global__ __launch_bounds__(512) void lstm_kernel(
    const float* __restrict__ batch, const float* __restrict__ W_ih,
    const float* __restrict__ W_hh, const float* __restrict__ b_ih,
    const float* __restrict__ b_hh, const _Float16* __restrict__ w1h,
    const float* __restrict__ b1, const float* __restrict__ W2,
    const float* __restrict__ b2, float* __restrict__ out) {
  __shared__ _Float16 hist[16 * SLOT];
  __shared__ _Float16 xs[2 * 4096];  // [buf][t(8)][elem(16) x k(32)]

  const int tid = (int)threadIdx.x;
  const int lane = tid & 63;
  const int w = tid >> 6;
  const int lq = lane >> 4;
  const int lr = lane & 15;
  const int b0 = (int)blockIdx.x * 16;

  // constant A-fragments (LSTM weights)
  half8 wx, wh;
  {
    int grow = (lr & 3) * 32 + w * 4 + (lr >> 2);
#pragma unroll
    for (int j = 0; j < 8; ++j) {
      int k = lq * 8 + j;
      wx[j] = (k < D_) ? (_Float16)W_ih[grow * D_ + k] : (_Float16)0.0f;
      wh[j] = (_Float16)W_hh[grow * H_ + k];
    }
  }
  f32x4 bias4;
#pragma unroll
  for (int r = 0; r < 4; ++r) {
    int g = r * 32 + w * 4 + lq;
    bias4[r] = b_ih[g] + b_hh[g];
  }

  // fragment-read offset (row = elem, 32-half rows, chunk-swizzled)
  const int rdo = lr * 32 + ((lq ^ ((lr >> 1) & 3)) << 3);
  const int kcol = w * 4 + lq;
  const int wro = lr * 32 + ((((kcol >> 3) ^ ((lr >> 1) & 3))) << 3) + (kcol & 7);

  // W1 fragment pointers: wave w covers n_out [w*64, w*64+64), 4 tiles of 16.
  // A-frag: lane (lq,lr) reads W1h[(w*64 + nt*16 + lr)*GK + k + lq*8], 16B.
  const _Float16* wp[4];
#pragma unroll
  for (int nt = 0; nt < 4; ++nt)
    wp[nt] = w1h + (size_t)(w * 64 + nt * 16 + lr) * GK + lq * 8;

  // gemm accumulators: gacc[nt][r] = hid[elem lr][n = w*64 + nt*16 + lq*4 + r]
  f32x4 gacc[4];
#pragma unroll
  for (int nt = 0; nt < 4; ++nt) {
    gacc[nt][0] = 0.f; gacc[nt][1] = 0.f; gacc[nt][2] = 0.f; gacc[nt][3] = 0.f;
  }

  // x slab staging: 576 float4 per 8t; thread -> (elem e, q-th float4 of 36)
  const int e0 = tid / 36, q0 = tid - e0 * 36;
  const int i1 = tid + 512;
  const int e1 = i1 / 36, q1 = i1 - e1 * 36;  // only tid<64
  const float* xld0 = batch + (size_t)(b0 + e0) * (T_ * D_) + q0 * 4;
  const float* xld1 = batch + (size_t)(b0 + e1) * (T_ * D_) + q1 * 4;
  float4 xv0, xv1;

#define XLOAD(tb)                                                              \
  do {                                                                         \
    xv0 = *(const float4*)(xld0 + (tb) * 144);                                 \
    if (tid < 64) xv1 = *(const float4*)(xld1 + (tb) * 144);                   \
  } while (0)

#define XPUT(E, Q, V, buf)                                                     \
  do {                                                                         \
    int swz_ = ((E) >> 1) & 3;                                                 \
    _Pragma("unroll") for (int j = 0; j < 4; ++j) {                            \
      int f_ = (Q) * 4 + j;                                                    \
      int to_ = (f_ * 57) >> 10; /* f/18 for f<1024 */                         \
      int d_ = f_ - to_ * 18;                                                  \
      float val_ = (j == 0) ? (V).x : (j == 1) ? (V).y : (j == 2) ? (V).z : (V).w; \
      xs[(buf) * 4096 + to_ * 512 + (E) * 32 + (((d_ >> 3) ^ swz_) << 3) + (d_ & 7)] = \
          (_Float16)val_;                                                      \
    }                                                                          \
  } while (0)

#define XSTORE(buf)                                                            \
  do {                                                                         \
    XPUT(e0, q0, xv0, buf);                                                    \
    if (tid < 64) XPUT(e1, q1, xv1, buf);                                      \
  } while (0)

// step tt (0..7): h(t-1) from ring; AXC = bias + Wih*x(t); PRE computes next
// step's ax under the hf lgkm wait. Then the fused-gemm slice for window
// blk-1, slot tt: issue next W1 frags (WFN), consume current (WFC) with the
// po-slot h-frag. Activations (7 trans) close the step; barrier.
#define STEP(tt, AXC, WFC, WFN, PRE)                                           \
  do {                                                                         \
    _Float16* hrd = ((tt) == 0 ? po + 7 * SLOT : pr + ((tt)-1) * SLOT);        \
    half8 hf = *(const half8*)&hrd[rdo];                                       \
    f32x4 acc = __builtin_amdgcn_mfma_f32_16x16x32_f16(wh, hf, AXC, 0, 0, 0);  \
    PRE;                                                                       \
    if (blk) {                                                                 \
      if ((tt) < 7) {                                                          \
        _Pragma("unroll") for (int nt = 0; nt < 4; ++nt) {                     \
          WFN[nt] = *(const half8*)wp[nt];                                     \
          wp[nt] += 32;                                                        \
        }                                                                      \
      }                                                                        \
      half8 gb = *(const half8*)&po[(tt) * SLOT + rdo];                        \
      _Pragma("unroll") for (int nt = 0; nt < 4; ++nt)                         \
        gacc[nt] = __builtin_amdgcn_mfma_f32_16x16x32_f16(WFC[nt], gb,         \
                                                          gacc[nt], 0, 0, 0); \
    }                                                                          \
    float ei = X2_(-K1_ * acc[0]);                                             \
    float ef = X2_(-K1_ * acc[1]);                                             \
    float eg = X2_(-K2_ * acc[2]);                                             \
    float eo = X2_(-K1_ * acc[3]);                                             \
    float pi_ = (1.0f + ei) * (1.0f + eg);                                     \
    float num = fmaf(c, pi_, (1.0f + ef) * (1.0f - eg));                       \
    c = num * RCP_((1.0f + ef) * pi_);                                         \
    float ec = X2_(-K2_ * c);                                                  \
    float h = (1.0f - ec) * RCP_((1.0f + eo) * (1.0f + ec));                   \
    pr[(tt)*SLOT + wro] = (_Float16)h;                                         \
    ldsbar();                                                                  \
  } while (0)

  XLOAD(0);  // loads fly while we zero LDS
  for (int i = tid; i < 16 * SLOT; i += 512) hist[i] = (_Float16)0.0f;
  for (int i = tid; i < 8192; i += 512) xs[i] = (_Float16)0.0f;
  ldsbar();
  XSTORE(0);   // one-time vmcnt wait
  XLOAD(1);
  ldsbar();

  float c = 0.0f;
  for (int blk = 0; blk < 32; ++blk) {
    const int p = blk & 1;
    _Float16* pr = hist + p * (8 * SLOT);
    _Float16* po = hist + (p ^ 1) * (8 * SLOT);
    const int xo = p * 4096;

    // preload the whole window's x fragments into registers
    half8 xq[8];
#pragma unroll
    for (int j = 0; j < 8; ++j) xq[j] = *(const half8*)&xs[xo + j * 512 + rdo];
    f32x4 ax0, ax1;
    ax0 = __builtin_amdgcn_mfma_f32_16x16x32_f16(wx, xq[0], bias4, 0, 0, 0);

    // W1 frag prefetch for slot 0 of k-window blk-1
    half8 wfA[4], wfB[4];
    if (blk) {
#pragma unroll
      for (int nt = 0; nt < 4; ++nt) {
        wfA[nt] = *(const half8*)wp[nt];
        wp[nt] += 32;
      }
    }

    STEP(0, ax0, wfA, wfB, ax1 = __builtin_amdgcn_mfma_f32_16x16x32_f16(wx, xq[1], bias4, 0, 0, 0));
    STEP(1, ax1, wfB, wfA, ax0 = __builtin_amdgcn_mfma_f32_16x16x32_f16(wx, xq[2], bias4, 0, 0, 0));
    STEP(2, ax0, wfA, wfB, ax1 = __builtin_amdgcn_mfma_f32_16x16x32_f16(wx, xq[3], bias4, 0, 0, 0));
    STEP(3, ax1, wfB, wfA, ax0 = __builtin_amdgcn_mfma_f32_16x16x32_f16(wx, xq[4], bias4, 0, 0, 0));
    // stage next slab mid-window (vmcnt: loads issued a full window ago)
    if (blk < 31) XSTORE(p ^ 1);
    if (blk < 30) XLOAD(blk + 2);
    STEP(4, ax0, wfA, wfB, ax1 = __builtin_amdgcn_mfma_f32_16x16x32_f16(wx, xq[5], bias4, 0, 0, 0));
    STEP(5, ax1, wfB, wfA, ax0 = __builtin_amdgcn_mfma_f32_16x16x32_f16(wx, xq[6], bias4, 0, 0, 0));
    STEP(6, ax0, wfA, wfB, ax1 = __builtin_amdgcn_mfma_f32_16x16x32_f16(wx, xq[7], bias4, 0, 0, 0));
    STEP(7, ax1, wfB, wfA, );
  }

  // ---- epilogue 1: gemm for the final k-window (window 31, ring parity 1)
  {
    const _Float16* pe = hist + 8 * SLOT;
#pragma unroll
    for (int tt = 0; tt < 8; ++tt) {
      half8 gb = *(const half8*)&pe[tt * SLOT + rdo];
#pragma unroll
      for (int nt = 0; nt < 4; ++nt) {
        half8 ga = *(const half8*)wp[nt];
        wp[nt] += 32;
        gacc[nt] = __builtin_amdgcn_mfma_f32_16x16x32_f16(ga, gb, gacc[nt], 0, 0, 0);
      }
    }
  }

  // ---- epilogue 2: bias + relu + W2 dot, reduce over n ----
  float s = 0.0f;
#pragma unroll
  for (int nt = 0; nt < 4; ++nt) {
    float4 b1v = ((const float4*)b1)[w * 16 + nt * 4 + lq];
    float4 w2v = ((const float4*)W2)[w * 16 + nt * 4 + lq];
#pragma unroll
    for (int r = 0; r < 4; ++r) {
      float t = gacc[nt][r] + ((const float*)&b1v)[r];
      t = fmaxf(t, 0.0f);
      s = fmaf(t, ((const float*)&w2v)[r], s);
    }
  }
  // sum over lq (lanes differing in bits 4/5): every lane ends with the
  // per-elem (lr) partial for its wave
  s += __shfl_xor(s, 16);
  s += __shfl_xor(s, 32);
  float* red = (float*)xs;  // xs is dead now; reuse as [8 waves][16 elems]
  if (lane < 16) red[w * 16 + lane] = s;
  ldsbar();
  if (tid < 16) {
    float t = 0.0f;
#pragma unroll
    for (int ww = 0; ww < 8; ++ww) t += red[ww * 16 + tid];
    out[b0 + tid] = t + b2[0];
  }
#undef STEP
#undef XSTORE
#undef XPUT
#undef XLOAD
}

extern "C" void kernel_launch(void* const* d_in, const int* in_sizes, int n_in,
                              void* d_out, int out_size, void* d_ws, size_t ws_size,
                              hipStream_t stream) {
  const float* batch = (const float*)d_in[0];
  const float* W_ih = (const float*)d_in[1];
  const float* W_hh = (const float*)d_in[2];
  const float* b_ih = (const float*)d_in[3];
  const float* b_hh = (const float*)d_in[4];
  const float* W1 = (const float*)d_in[5];
  const float* b1 = (const float*)d_in[6];
  const float* W2 = (const float*)d_in[7];
  const float* b2 = (const float*)d_in[8];
  float* out = (float*)d_out;

  char* ws = (char*)d_ws;
  _Float16* w1h = (_Float16*)ws;  // 512*8192*2 = 8388608 B (only workspace user)

  cvtw1_kernel<<<4096, 256, 0, stream>>>(W1, (unsigned short*)w1h);
  lstm_kernel<<<256, 512, 0, stream>>>(batch, W_ih, W_hh, b_ih, b_hh,
                                       w1h, b1, W2, b2, out);
}

// Round 11
// 230.488 us; speedup vs baseline: 1.6641x; 1.6641x over previous
//
#include <hip/hip_runtime.h>
#include <hip/hip_bf16.h>
#include <stdint.h>

typedef float f32x4 __attribute__((ext_vector_type(4)));
typedef _Float16 half8 __attribute__((ext_vector_type(8)));

#define B_ 4096
#define T_ 256
#define D_ 18
#define H_ 32
#define GK 8192   // T_*H_
#define GN 512
#define KSPLIT 4
#define SLOT 520  // hist ring slot stride in halves (16*32 + 8 pad)

#define K1_ 1.442695041f
#define K2_ 2.885390082f
#define X2_ __builtin_amdgcn_exp2f
#define RCP_ __builtin_amdgcn_rcpf

// Barrier draining ONLY LDS (lgkmcnt) — global loads/stores stay in flight.
__device__ __forceinline__ void ldsbar() {
  asm volatile("s_waitcnt lgkmcnt(0)\n\ts_barrier" ::: "memory");
}
// async global -> LDS, 16B per lane. LDS dest must be wave-uniform base
// (HW adds lane*16); global src is per-lane (carries the swizzle).
__device__ __forceinline__ void gl_lds16(const _Float16* g, _Float16* l) {
  __builtin_amdgcn_global_load_lds(
      (const __attribute__((address_space(1))) unsigned int*)g,
      (__attribute__((address_space(3))) unsigned int*)l, 16, 0, 0);
}

// ---------- kernel 1: W1 fp32 -> fp16 (RNE) ----------
__global__ __launch_bounds__(256) void cvtw1_kernel(const float* __restrict__ w1,
                                                    unsigned short* __restrict__ dst) {
  int i = blockIdx.x * 256 + threadIdx.x;  // float4 index, total 1048576
  float4 v = ((const float4*)w1)[i];
  unsigned short a = __builtin_bit_cast(unsigned short, (_Float16)v.x);
  unsigned short b = __builtin_bit_cast(unsigned short, (_Float16)v.y);
  unsigned short c = __builtin_bit_cast(unsigned short, (_Float16)v.z);
  unsigned short d = __builtin_bit_cast(unsigned short, (_Float16)v.w);
  uint2 o; o.x = (unsigned)a | ((unsigned)b << 16); o.y = (unsigned)c | ((unsigned)d << 16);
  ((uint2*)dst)[i] = o;
}

// ---------- kernel 2: MFMA LSTM (R3-proven; DO NOT TOUCH) ----------
// Block = 512 thr (8 waves) owns 16 batch elems. Verified best across R1-R10:
// 4-wave (R2), barrier-free (R5), 8-elem 2-convoy (R7), fused-gemm (R9) all lost.
__global__ __launch_bounds__(512) void lstm_kernel(
    const float* __restrict__ batch, const float* __restrict__ W_ih,
    const float* __restrict__ W_hh, const float* __restrict__ b_ih,
    const float* __restrict__ b_hh, _Float16* __restrict__ hs) {
  __shared__ _Float16 hist[16 * SLOT];
  __shared__ _Float16 xs[2 * 4096];  // [buf][t(8)][elem(16) x k(32)]

  const int tid = (int)threadIdx.x;
  const int lane = tid & 63;
  const int w = tid >> 6;
  const int lq = lane >> 4;
  const int lr = lane & 15;
  const int b0 = (int)blockIdx.x * 16;

  // constant A-fragments
  half8 wx, wh;
  {
    int grow = (lr & 3) * 32 + w * 4 + (lr >> 2);
#pragma unroll
    for (int j = 0; j < 8; ++j) {
      int k = lq * 8 + j;
      wx[j] = (k < D_) ? (_Float16)W_ih[grow * D_ + k] : (_Float16)0.0f;
      wh[j] = (_Float16)W_hh[grow * H_ + k];
    }
  }
  f32x4 bias4;
#pragma unroll
  for (int r = 0; r < 4; ++r) {
    int g = r * 32 + w * 4 + lq;
    bias4[r] = b_ih[g] + b_hh[g];
  }

  // fragment-read offset (row = elem, 32-half rows, chunk-swizzled)
  const int rdo = lr * 32 + ((lq ^ ((lr >> 1) & 3)) << 3);
  const int kcol = w * 4 + lq;
  const int wro = lr * 32 + ((((kcol >> 3) ^ ((lr >> 1) & 3))) << 3) + (kcol & 7);

  // flush mapping (ring -> hs, coalesced 16B/lane)
  const int fe = tid >> 5;
  const int fs = (tid >> 2) & 7;
  const int fg = tid & 3;
  const int fl_rd = fs * SLOT + fe * 32 + ((fg ^ ((fe >> 1) & 3)) << 3);
  _Float16* fl_wp = hs + (size_t)(b0 + fe) * GK + fs * H_ + fg * 8;

  // x slab staging: 576 float4 per 8t; thread -> (elem e, q-th float4 of 36)
  const int e0 = tid / 36, q0 = tid - e0 * 36;
  const int i1 = tid + 512;
  const int e1 = i1 / 36, q1 = i1 - e1 * 36;  // only tid<64
  const float* xld0 = batch + (size_t)(b0 + e0) * (T_ * D_) + q0 * 4;
  const float* xld1 = batch + (size_t)(b0 + e1) * (T_ * D_) + q1 * 4;
  float4 xv0, xv1;

#define XLOAD(tb)                                                              \
  do {                                                                         \
    xv0 = *(const float4*)(xld0 + (tb) * 144);                                 \
    if (tid < 64) xv1 = *(const float4*)(xld1 + (tb) * 144);                   \
  } while (0)

#define XPUT(E, Q, V, buf)                                                     \
  do {                                                                         \
    int swz_ = ((E) >> 1) & 3;                                                 \
    _Pragma("unroll") for (int j = 0; j < 4; ++j) {                            \
      int f_ = (Q) * 4 + j;                                                    \
      int to_ = (f_ * 57) >> 10; /* f/18 for f<1024 */                         \
      int d_ = f_ - to_ * 18;                                                  \
      float val_ = (j == 0) ? (V).x : (j == 1) ? (V).y : (j == 2) ? (V).z : (V).w; \
      xs[(buf) * 4096 + to_ * 512 + (E) * 32 + (((d_ >> 3) ^ swz_) << 3) + (d_ & 7)] = \
          (_Float16)val_;                                                      \
    }                                                                          \
  } while (0)

#define XSTORE(buf)                                                            \
  do {                                                                         \
    XPUT(e0, q0, xv0, buf);                                                    \
    if (tid < 64) XPUT(e1, q1, xv1, buf);                                      \
  } while (0)

// step tt (0..7): h(t-1) from ring; AXC holds bias + Wih*x(t); PRE computes
// next step's ax under the hf lgkm wait. Merged activations (7 trans):
//   c' = [c*(1+ei)(1+eg) + (1+ef)(1-eg)] / [(1+ef)(1+ei)(1+eg)]
//   h  = (1-ec) / [(1+eo)(1+ec)]
#define STEP(tt, AXC, PRE)                                                     \
  do {                                                                         \
    _Float16* hrd = ((tt) == 0 ? po + 7 * SLOT : pr + ((tt)-1) * SLOT);        \
    half8 hf = *(const half8*)&hrd[rdo];                                       \
    f32x4 acc = __builtin_amdgcn_mfma_f32_16x16x32_f16(wh, hf, AXC, 0, 0, 0);  \
    PRE;                                                                       \
    float ei = X2_(-K1_ * acc[0]);                                             \
    float ef = X2_(-K1_ * acc[1]);                                             \
    float eg = X2_(-K2_ * acc[2]);                                             \
    float eo = X2_(-K1_ * acc[3]);                                             \
    float pi_ = (1.0f + ei) * (1.0f + eg);                                     \
    float num = fmaf(c, pi_, (1.0f + ef) * (1.0f - eg));                       \
    c = num * RCP_((1.0f + ef) * pi_);                                         \
    float ec = X2_(-K2_ * c);                                                  \
    float h = (1.0f - ec) * RCP_((1.0f + eo) * (1.0f + ec));                   \
    pr[(tt)*SLOT + wro] = (_Float16)h;                                         \
    ldsbar();                                                                  \
  } while (0)

  XLOAD(0);  // loads fly while we zero LDS
  for (int i = tid; i < 16 * SLOT; i += 512) hist[i] = (_Float16)0.0f;
  for (int i = tid; i < 8192; i += 512) xs[i] = (_Float16)0.0f;
  ldsbar();
  XSTORE(0);   // one-time vmcnt wait
  XLOAD(1);
  ldsbar();

  float c = 0.0f;
  for (int blk = 0; blk < 32; ++blk) {
    const int p = blk & 1;
    _Float16* pr = hist + p * (8 * SLOT);
    _Float16* po = hist + (p ^ 1) * (8 * SLOT);
    const int xo = p * 4096;

    // preload the whole window's x fragments into registers
    half8 xq[8];
#pragma unroll
    for (int j = 0; j < 8; ++j) xq[j] = *(const half8*)&xs[xo + j * 512 + rdo];
    f32x4 ax0, ax1;
    ax0 = __builtin_amdgcn_mfma_f32_16x16x32_f16(wx, xq[0], bias4, 0, 0, 0);

    STEP(0, ax0, ax1 = __builtin_amdgcn_mfma_f32_16x16x32_f16(wx, xq[1], bias4, 0, 0, 0));
    STEP(1, ax1, ax0 = __builtin_amdgcn_mfma_f32_16x16x32_f16(wx, xq[2], bias4, 0, 0, 0));
    STEP(2, ax0, ax1 = __builtin_amdgcn_mfma_f32_16x16x32_f16(wx, xq[3], bias4, 0, 0, 0));
    STEP(3, ax1, ax0 = __builtin_amdgcn_mfma_f32_16x16x32_f16(wx, xq[4], bias4, 0, 0, 0));
    // stage next slab mid-window (vmcnt: loads issued a full window ago)
    if (blk < 31) XSTORE(p ^ 1);
    if (blk < 30) XLOAD(blk + 2);
    STEP(4, ax0, ax1 = __builtin_amdgcn_mfma_f32_16x16x32_f16(wx, xq[5], bias4, 0, 0, 0));
    // flush PREVIOUS window's ring half -> global (other parity, no barrier)
    if (blk) {
      half8 hv = *(const half8*)&hist[(p ^ 1) * (8 * SLOT) + fl_rd];
      *(half8*)(fl_wp + (size_t)(blk - 1) * (8 * H_)) = hv;
    }
    STEP(5, ax1, ax0 = __builtin_amdgcn_mfma_f32_16x16x32_f16(wx, xq[6], bias4, 0, 0, 0));
    STEP(6, ax0, ax1 = __builtin_amdgcn_mfma_f32_16x16x32_f16(wx, xq[7], bias4, 0, 0, 0));
    STEP(7, ax1, );
  }
  // final flush (window 31, parity 1)
  {
    half8 hv = *(const half8*)&hist[8 * SLOT + fl_rd];
    *(half8*)(fl_wp + (size_t)31 * (8 * H_)) = hv;
  }
#undef STEP
#undef XSTORE
#undef XPUT
#undef XLOAD
}

// ---------- kernel 3: fp16 MFMA GEMM, BM=BN=128 BK=64, split-K=4 ----------
// R4-proven pipeline (best measured): counted-vmcnt. Prologue stages BOTH
// buffers (16 loads in flight). Per iteration: vmcnt(8)+bar -> ds_read frags
// -> lgkm(0)+bar -> restage this buf for it+2 -> MFMA. No vmcnt(0) drain in
// main loop. R11 change: part stored as fp16 (f32 accum in-register; halves
// part write + head read bytes; partials ~O(0.3) so fp16 error ~1e-4).
__global__ __launch_bounds__(256, 2) void gemm_kernel(
    const _Float16* __restrict__ Ahs, const _Float16* __restrict__ Bw1,
    _Float16* __restrict__ part) {
  __shared__ _Float16 As[2 * 128 * 64];
  __shared__ _Float16 Bs[2 * 128 * 64];

  const int bid = (int)blockIdx.x;
  const int m0 = (bid & 31) << 7;
  const int n0 = ((bid >> 5) & 3) << 7;
  const int ksp = bid >> 7;
  const int k0 = ksp << 11;   // * 2048
  _Float16* outp = part + (size_t)ksp * ((size_t)B_ * GN);

  const int tid = (int)threadIdx.x;
  const int lane = tid & 63, w = tid >> 6;
  const int wm = w & 1, wn = w >> 1;
  const int lq = lane >> 4, lr = lane & 15;

  // global sources (per-lane, swizzled) + LDS dests (wave-uniform base)
  const _Float16* gA[4]; const _Float16* gB[4];
  _Float16* lA[4]; _Float16* lB[4];
#pragma unroll
  for (int j = 0; j < 4; ++j) {
    int p = tid + 256 * j;               // 0..1023
    int row = p >> 3, q = p & 7, cg = q ^ (row & 7);
    gA[j] = Ahs + (size_t)(m0 + row) * GK + k0 + cg * 8;
    gB[j] = Bw1 + (size_t)(n0 + row) * GK + k0 + cg * 8;
    int wbase = (w * 64 + 256 * j) * 8;  // halves; HW adds lane*16B
    lA[j] = As + wbase;
    lB[j] = Bs + wbase;
  }

  int offA[4][2], offB[4][2];
#pragma unroll
  for (int mt = 0; mt < 4; ++mt)
#pragma unroll
    for (int ks = 0; ks < 2; ++ks) {
      int m = wm * 64 + mt * 16 + lr;
      offA[mt][ks] = m * 64 + (((lq + ks * 4) ^ (m & 7)) << 3);
      int n = wn * 64 + mt * 16 + lr;
      offB[mt][ks] = n * 64 + (((lq + ks * 4) ^ (n & 7)) << 3);
    }

  f32x4 acc[4][4];
#pragma unroll
  for (int mt = 0; mt < 4; ++mt)
#pragma unroll
    for (int nt = 0; nt < 4; ++nt) {
      acc[mt][nt][0] = 0.f; acc[mt][nt][1] = 0.f;
      acc[mt][nt][2] = 0.f; acc[mt][nt][3] = 0.f;
    }

#define STAGE(POFF)                                                            \
  do {                                                                         \
    _Pragma("unroll") for (int j = 0; j < 4; ++j) {                            \
      gl_lds16(gA[j], lA[j] + (POFF));                                         \
      gl_lds16(gB[j], lB[j] + (POFF));                                         \
      gA[j] += 64; gB[j] += 64;                                                \
    }                                                                          \
  } while (0)

#define FRAGS(POFF)                                                            \
  half8 af[4][2], bf[4][2];                                                    \
  _Pragma("unroll") for (int mt = 0; mt < 4; ++mt)                             \
    _Pragma("unroll") for (int ks = 0; ks < 2; ++ks) {                         \
      af[mt][ks] = *(const half8*)&As[(POFF) + offA[mt][ks]];                  \
      bf[mt][ks] = *(const half8*)&Bs[(POFF) + offB[mt][ks]];                  \
    }

#define MFMAS                                                                  \
  _Pragma("unroll") for (int ks = 0; ks < 2; ++ks)                             \
    _Pragma("unroll") for (int mt = 0; mt < 4; ++mt)                           \
      _Pragma("unroll") for (int nt = 0; nt < 4; ++nt)                         \
        acc[mt][nt] = __builtin_amdgcn_mfma_f32_16x16x32_f16(                  \
            af[mt][ks], bf[nt][ks], acc[mt][nt], 0, 0, 0);

  STAGE(0);      // buf0 <- k-chunk 0
  STAGE(8192);   // buf1 <- k-chunk 1   (16 loads in flight)

  for (int it = 0; it < 31; ++it) {
    const int POFF = (it & 1) * 8192;
    // current buffer's 8 loads (oldest) landed; next buffer's 8 keep flying
    asm volatile("s_waitcnt vmcnt(8)\n\ts_barrier" ::: "memory");
    FRAGS(POFF);
    // all waves finished reading this buffer -> safe to overwrite
    asm volatile("s_waitcnt lgkmcnt(0)\n\ts_barrier" ::: "memory");
    if (it < 30) STAGE(POFF);   // refill for it+2, flies over the MFMAs
    MFMAS;
  }
  {  // it = 31 (peeled: only 8 loads outstanding -> full drain)
    asm volatile("s_waitcnt vmcnt(0)\n\ts_barrier" ::: "memory");
    FRAGS(8192);
    MFMAS;
  }
#undef MFMAS
#undef FRAGS
#undef STAGE

  // epilogue: C layout col=lr, row=lq*4+reg; fp16 stores to this split's buffer
#pragma unroll
  for (int mt = 0; mt < 4; ++mt)
#pragma unroll
    for (int nt = 0; nt < 4; ++nt) {
      int n = n0 + wn * 64 + nt * 16 + lr;
#pragma unroll
      for (int r = 0; r < 4; ++r) {
        int m = m0 + wm * 64 + mt * 16 + lq * 4 + r;
        outp[(size_t)m * GN + n] = (_Float16)acc[mt][nt][r];
      }
    }
}

// ---------- kernel 4: head — sum KSPLIT fp16 partials, bias, relu, dot W2 ----
__global__ __launch_bounds__(256) void head_kernel(const _Float16* __restrict__ part,
                                                   const float* __restrict__ b1,
                                                   const float* __restrict__ W2,
                                                   const float* __restrict__ b2,
                                                   float* __restrict__ out) {
  const int b = (int)(blockIdx.x * 4 + (threadIdx.x >> 6));
  const int l = (int)(threadIdx.x & 63);
  const size_t stride = (size_t)B_ * GN;   // in halves
  // lane l owns n = l*8 .. l*8+7 (one half8, coalesced 16B/lane)
  half8 hv = ((const half8*)(part + (size_t)b * GN))[l];
  float a8[8];
#pragma unroll
  for (int j = 0; j < 8; ++j) a8[j] = (float)hv[j];
#pragma unroll
  for (int sp = 1; sp < KSPLIT; ++sp) {
    half8 pv = ((const half8*)(part + sp * stride + (size_t)b * GN))[l];
#pragma unroll
    for (int j = 0; j < 8; ++j) a8[j] += (float)pv[j];
  }
  float4 bv0 = ((const float4*)b1)[2 * l];
  float4 bv1 = ((const float4*)b1)[2 * l + 1];
  float4 wv0 = ((const float4*)W2)[2 * l];
  float4 wv1 = ((const float4*)W2)[2 * l + 1];
  float s = 0.0f;
  s = fmaf(fmaxf(a8[0] + bv0.x, 0.0f), wv0.x, s);
  s = fmaf(fmaxf(a8[1] + bv0.y, 0.0f), wv0.y, s);
  s = fmaf(fmaxf(a8[2] + bv0.z, 0.0f), wv0.z, s);
  s = fmaf(fmaxf(a8[3] + bv0.w, 0.0f), wv0.w, s);
  s = fmaf(fmaxf(a8[4] + bv1.x, 0.0f), wv1.x, s);
  s = fmaf(fmaxf(a8[5] + bv1.y, 0.0f), wv1.y, s);
  s = fmaf(fmaxf(a8[6] + bv1.z, 0.0f), wv1.z, s);
  s = fmaf(fmaxf(a8[7] + bv1.w, 0.0f), wv1.w, s);
#pragma unroll
  for (int off = 32; off >= 1; off >>= 1) s += __shfl_xor(s, off);
  if (l == 0) out[b] = s + b2[0];
}

extern "C" void kernel_launch(void* const* d_in, const int* in_sizes, int n_in,
                              void* d_out, int out_size, void* d_ws, size_t ws_size,
                              hipStream_t stream) {
  const float* batch = (const float*)d_in[0];
  const float* W_ih = (const float*)d_in[1];
  const float* W_hh = (const float*)d_in[2];
  const float* b_ih = (const float*)d_in[3];
  const float* b_hh = (const float*)d_in[4];
  const float* W1 = (const float*)d_in[5];
  const float* b1 = (const float*)d_in[6];
  const float* W2 = (const float*)d_in[7];
  const float* b2 = (const float*)d_in[8];
  float* out = (float*)d_out;

  char* ws = (char*)d_ws;
  _Float16* hs = (_Float16*)ws;                         // 4096*8192*2 = 67108864 B
  _Float16* w1h = (_Float16*)(ws + 67108864);           // 512*8192*2  =  8388608 B
  _Float16* part = (_Float16*)(ws + 67108864 + 8388608); // 4*4096*512*2 = 16777216 B

  cvtw1_kernel<<<4096, 256, 0, stream>>>(W1, (unsigned short*)w1h);
  lstm_kernel<<<256, 512, 0, stream>>>(batch, W_ih, W_hh, b_ih, b_hh, hs);
  gemm_kernel<<<512, 256, 0, stream>>>(hs, w1h, part);
  head_kernel<<<1024, 256, 0, stream>>>(part, b1, W2, b2, out);
}

// Round 12
// 230.130 us; speedup vs baseline: 1.6667x; 1.0016x over previous
//
#include <hip/hip_runtime.h>
#include <hip/hip_bf16.h>
#include <stdint.h>

typedef float f32x4 __attribute__((ext_vector_type(4)));
typedef _Float16 half8 __attribute__((ext_vector_type(8)));

#define B_ 4096
#define T_ 256
#define D_ 18
#define H_ 32
#define GK 8192   // T_*H_
#define GN 512
#define KSPLIT 8
#define SLOT 520  // hist ring slot stride in halves (16*32 + 8 pad)

#define K1_ 1.442695041f
#define K2_ 2.885390082f
#define X2_ __builtin_amdgcn_exp2f
#define RCP_ __builtin_amdgcn_rcpf

// Barrier draining ONLY LDS (lgkmcnt) — global loads/stores stay in flight.
__device__ __forceinline__ void ldsbar() {
  asm volatile("s_waitcnt lgkmcnt(0)\n\ts_barrier" ::: "memory");
}
// async global -> LDS, 16B per lane. LDS dest must be wave-uniform base
// (HW adds lane*16); global src is per-lane (carries the swizzle).
__device__ __forceinline__ void gl_lds16(const _Float16* g, _Float16* l) {
  __builtin_amdgcn_global_load_lds(
      (const __attribute__((address_space(1))) unsigned int*)g,
      (__attribute__((address_space(3))) unsigned int*)l, 16, 0, 0);
}

// ---------- kernel 1: W1 fp32 -> fp16 (RNE) ----------
__global__ __launch_bounds__(256) void cvtw1_kernel(const float* __restrict__ w1,
                                                    unsigned short* __restrict__ dst) {
  int i = blockIdx.x * 256 + threadIdx.x;  // float4 index, total 1048576
  float4 v = ((const float4*)w1)[i];
  unsigned short a = __builtin_bit_cast(unsigned short, (_Float16)v.x);
  unsigned short b = __builtin_bit_cast(unsigned short, (_Float16)v.y);
  unsigned short c = __builtin_bit_cast(unsigned short, (_Float16)v.z);
  unsigned short d = __builtin_bit_cast(unsigned short, (_Float16)v.w);
  uint2 o; o.x = (unsigned)a | ((unsigned)b << 16); o.y = (unsigned)c | ((unsigned)d << 16);
  ((uint2*)dst)[i] = o;
}

// ---------- kernel 2: MFMA LSTM (R3-proven; DO NOT TOUCH) ----------
__global__ __launch_bounds__(512) void lstm_kernel(
    const float* __restrict__ batch, const float* __restrict__ W_ih,
    const float* __restrict__ W_hh, const float* __restrict__ b_ih,
    const float* __restrict__ b_hh, _Float16* __restrict__ hs) {
  __shared__ _Float16 hist[16 * SLOT];
  __shared__ _Float16 xs[2 * 4096];  // [buf][t(8)][elem(16) x k(32)]

  const int tid = (int)threadIdx.x;
  const int lane = tid & 63;
  const int w = tid >> 6;
  const int lq = lane >> 4;
  const int lr = lane & 15;
  const int b0 = (int)blockIdx.x * 16;

  // constant A-fragments
  half8 wx, wh;
  {
    int grow = (lr & 3) * 32 + w * 4 + (lr >> 2);
#pragma unroll
    for (int j = 0; j < 8; ++j) {
      int k = lq * 8 + j;
      wx[j] = (k < D_) ? (_Float16)W_ih[grow * D_ + k] : (_Float16)0.0f;
      wh[j] = (_Float16)W_hh[grow * H_ + k];
    }
  }
  f32x4 bias4;
#pragma unroll
  for (int r = 0; r < 4; ++r) {
    int g = r * 32 + w * 4 + lq;
    bias4[r] = b_ih[g] + b_hh[g];
  }

  // fragment-read offset (row = elem, 32-half rows, chunk-swizzled)
  const int rdo = lr * 32 + ((lq ^ ((lr >> 1) & 3)) << 3);
  const int kcol = w * 4 + lq;
  const int wro = lr * 32 + ((((kcol >> 3) ^ ((lr >> 1) & 3))) << 3) + (kcol & 7);

  // flush mapping (ring -> hs, coalesced 16B/lane)
  const int fe = tid >> 5;
  const int fs = (tid >> 2) & 7;
  const int fg = tid & 3;
  const int fl_rd = fs * SLOT + fe * 32 + ((fg ^ ((fe >> 1) & 3)) << 3);
  _Float16* fl_wp = hs + (size_t)(b0 + fe) * GK + fs * H_ + fg * 8;

  // x slab staging: 576 float4 per 8t; thread -> (elem e, q-th float4 of 36)
  const int e0 = tid / 36, q0 = tid - e0 * 36;
  const int i1 = tid + 512;
  const int e1 = i1 / 36, q1 = i1 - e1 * 36;  // only tid<64
  const float* xld0 = batch + (size_t)(b0 + e0) * (T_ * D_) + q0 * 4;
  const float* xld1 = batch + (size_t)(b0 + e1) * (T_ * D_) + q1 * 4;
  float4 xv0, xv1;

#define XLOAD(tb)                                                              \
  do {                                                                         \
    xv0 = *(const float4*)(xld0 + (tb) * 144);                                 \
    if (tid < 64) xv1 = *(const float4*)(xld1 + (tb) * 144);                   \
  } while (0)

#define XPUT(E, Q, V, buf)                                                     \
  do {                                                                         \
    int swz_ = ((E) >> 1) & 3;                                                 \
    _Pragma("unroll") for (int j = 0; j < 4; ++j) {                            \
      int f_ = (Q) * 4 + j;                                                    \
      int to_ = (f_ * 57) >> 10; /* f/18 for f<1024 */                         \
      int d_ = f_ - to_ * 18;                                                  \
      float val_ = (j == 0) ? (V).x : (j == 1) ? (V).y : (j == 2) ? (V).z : (V).w; \
      xs[(buf) * 4096 + to_ * 512 + (E) * 32 + (((d_ >> 3) ^ swz_) << 3) + (d_ & 7)] = \
          (_Float16)val_;                                                      \
    }                                                                          \
  } while (0)

#define XSTORE(buf)                                                            \
  do {                                                                         \
    XPUT(e0, q0, xv0, buf);                                                    \
    if (tid < 64) XPUT(e1, q1, xv1, buf);                                      \
  } while (0)

#define STEP(tt, AXC, PRE)                                                     \
  do {                                                                         \
    _Float16* hrd = ((tt) == 0 ? po + 7 * SLOT : pr + ((tt)-1) * SLOT);        \
    half8 hf = *(const half8*)&hrd[rdo];                                       \
    f32x4 acc = __builtin_amdgcn_mfma_f32_16x16x32_f16(wh, hf, AXC, 0, 0, 0);  \
    PRE;                                                                       \
    float ei = X2_(-K1_ * acc[0]);                                             \
    float ef = X2_(-K1_ * acc[1]);                                             \
    float eg = X2_(-K2_ * acc[2]);                                             \
    float eo = X2_(-K1_ * acc[3]);                                             \
    float pi_ = (1.0f + ei) * (1.0f + eg);                                     \
    float num = fmaf(c, pi_, (1.0f + ef) * (1.0f - eg));                       \
    c = num * RCP_((1.0f + ef) * pi_);                                         \
    float ec = X2_(-K2_ * c);                                                  \
    float h = (1.0f - ec) * RCP_((1.0f + eo) * (1.0f + ec));                   \
    pr[(tt)*SLOT + wro] = (_Float16)h;                                         \
    ldsbar();                                                                  \
  } while (0)

  XLOAD(0);  // loads fly while we zero LDS
  for (int i = tid; i < 16 * SLOT; i += 512) hist[i] = (_Float16)0.0f;
  for (int i = tid; i < 8192; i += 512) xs[i] = (_Float16)0.0f;
  ldsbar();
  XSTORE(0);   // one-time vmcnt wait
  XLOAD(1);
  ldsbar();

  float c = 0.0f;
  for (int blk = 0; blk < 32; ++blk) {
    const int p = blk & 1;
    _Float16* pr = hist + p * (8 * SLOT);
    _Float16* po = hist + (p ^ 1) * (8 * SLOT);
    const int xo = p * 4096;

    half8 xq[8];
#pragma unroll
    for (int j = 0; j < 8; ++j) xq[j] = *(const half8*)&xs[xo + j * 512 + rdo];
    f32x4 ax0, ax1;
    ax0 = __builtin_amdgcn_mfma_f32_16x16x32_f16(wx, xq[0], bias4, 0, 0, 0);

    STEP(0, ax0, ax1 = __builtin_amdgcn_mfma_f32_16x16x32_f16(wx, xq[1], bias4, 0, 0, 0));
    STEP(1, ax1, ax0 = __builtin_amdgcn_mfma_f32_16x16x32_f16(wx, xq[2], bias4, 0, 0, 0));
    STEP(2, ax0, ax1 = __builtin_amdgcn_mfma_f32_16x16x32_f16(wx, xq[3], bias4, 0, 0, 0));
    STEP(3, ax1, ax0 = __builtin_amdgcn_mfma_f32_16x16x32_f16(wx, xq[4], bias4, 0, 0, 0));
    if (blk < 31) XSTORE(p ^ 1);
    if (blk < 30) XLOAD(blk + 2);
    STEP(4, ax0, ax1 = __builtin_amdgcn_mfma_f32_16x16x32_f16(wx, xq[5], bias4, 0, 0, 0));
    if (blk) {
      half8 hv = *(const half8*)&hist[(p ^ 1) * (8 * SLOT) + fl_rd];
      *(half8*)(fl_wp + (size_t)(blk - 1) * (8 * H_)) = hv;
    }
    STEP(5, ax1, ax0 = __builtin_amdgcn_mfma_f32_16x16x32_f16(wx, xq[6], bias4, 0, 0, 0));
    STEP(6, ax0, ax1 = __builtin_amdgcn_mfma_f32_16x16x32_f16(wx, xq[7], bias4, 0, 0, 0));
    STEP(7, ax1, );
  }
  {
    half8 hv = *(const half8*)&hist[8 * SLOT + fl_rd];
    *(half8*)(fl_wp + (size_t)31 * (8 * H_)) = hv;
  }
#undef STEP
#undef XSTORE
#undef XPUT
#undef XLOAD
}

// ---------- kernel 3: fp16 MFMA GEMM — 8-phase 256x256, BK=64, KSPLIT=8 ----
// R18: 8-phase schedule (guide m198/m201 template, f16, chunk-XOR swizzle).
// 256 blocks (16m x 2n x 8ksp) x 512 thr (8 waves: wm=w>>2 in {0,1},
// wn=w&3 in {0..3}); per-wave output 128x64; LDS = 2buf x (256x64) A + B
// = 128 KB. Iter = 2 K-tiles (buf0/buf1); 8 phases per iter; per phase:
// 12 ds_read (one C-quadrant) -> 2 gl_lds stage issues -> barrier ->
// 16 MFMA (setprio) -> [vmcnt(0) at phases 4/8 only: at those points the
// ONLY outstanding loads are the tile about to be read] -> barrier.
// Staging windows: phases 1-4 stage tile 2it+1 (buf1, freed at prev ph8);
// phases 5-8 stage tile 2it+2 (buf0, freed at ph4). A staged at the first
// two phases of each window (longer flight — HBM-risk operand), B at the
// last two (L2-resident).
__global__ __launch_bounds__(512, 1) void gemm_kernel(
    const _Float16* __restrict__ Ahs, const _Float16* __restrict__ Bw1,
    _Float16* __restrict__ part) {
  __shared__ _Float16 As[2 * 256 * 64];   // 64 KB
  __shared__ _Float16 Bs[2 * 256 * 64];   // 64 KB

  const int bid = (int)blockIdx.x;
  const int m0 = (bid & 15) << 8;          // 16 m-blocks of 256
  const int n0 = ((bid >> 4) & 1) << 8;    // 2 n-blocks of 256
  const int ksp = bid >> 5;                // 8 k-splits
  const int k0 = ksp << 10;                // * 1024
  _Float16* outp = part + (size_t)ksp * ((size_t)B_ * GN);

  const int tid = (int)threadIdx.x;
  const int lane = tid & 63, w = tid >> 6;
  const int wm = w >> 2, wn = w & 3;
  const int lq = lane >> 4, lr = lane & 15;

  // staging: p = tid + 512*j covers (row = p>>3 in 0..255, chunk q = p&7);
  // global src pre-swizzled (cg = q ^ (row&7)); LDS dest linear p*16B.
  const _Float16* gA[4]; const _Float16* gB[4];
  _Float16* lAd[4]; _Float16* lBd[4];
#pragma unroll
  for (int j = 0; j < 4; ++j) {
    int p = tid + 512 * j;
    int row = p >> 3, q = p & 7, cg = q ^ (row & 7);
    gA[j] = Ahs + (size_t)(m0 + row) * GK + k0 + cg * 8;
    gB[j] = Bw1 + (size_t)(n0 + row) * GK + k0 + cg * 8;
    lAd[j] = As + (w * 64 + 512 * j) * 8;  // halves; HW adds lane*16B
    lBd[j] = Bs + (w * 64 + 512 * j) * 8;
  }

  // fragment read bases: row r, k-chunk g = lq + ks*4, slot = g ^ (r&7);
  // r&7 == lr&7 for all frag rows (row = base16* + lr), so the XOR term
  // depends only on (lq, ks, lr): xk[2].
  const int rA = (wm * 128 + lr) * 64;
  const int rB = (wn * 64 + lr) * 64;
  int xk[2];
  xk[0] = ((lq) ^ (lr & 7)) << 3;
  xk[1] = ((lq + 4) ^ (lr & 7)) << 3;

  f32x4 acc[8][4];
#pragma unroll
  for (int mt = 0; mt < 8; ++mt)
#pragma unroll
    for (int nt = 0; nt < 4; ++nt) {
      acc[mt][nt][0] = 0.f; acc[mt][nt][1] = 0.f;
      acc[mt][nt][2] = 0.f; acc[mt][nt][3] = 0.f;
    }

#define SA2(J0, J1, SBUF, T)                                                   \
  do {                                                                         \
    gl_lds16(gA[J0] + (size_t)(T) * 64, lAd[J0] + (SBUF) * 16384);             \
    gl_lds16(gA[J1] + (size_t)(T) * 64, lAd[J1] + (SBUF) * 16384);             \
  } while (0)
#define SB2(J0, J1, SBUF, T)                                                   \
  do {                                                                         \
    gl_lds16(gB[J0] + (size_t)(T) * 64, lBd[J0] + (SBUF) * 16384);             \
    gl_lds16(gB[J1] + (size_t)(T) * 64, lBd[J1] + (SBUF) * 16384);             \
  } while (0)

// phase: quadrant (MH in {0,1} -> m-half of 64 rows; NH in {0,1} -> n-half
// of 32 cols). RBUF = LDS buffer read this phase. STAGECODE issues 2 loads.
// TAILWAIT = optional vmcnt(0) validating the next reader's tile.
#define PHASE(RBUF, MH, NH, STAGECODE, TAILWAIT)                               \
  do {                                                                         \
    half8 af[4][2], bf[2][2];                                                  \
    _Pragma("unroll") for (int mt = 0; mt < 4; ++mt)                           \
      _Pragma("unroll") for (int ks = 0; ks < 2; ++ks)                         \
        af[mt][ks] = *(const half8*)&As[(RBUF) * 16384 + rA +                  \
                                        ((MH) * 64 + mt * 16) * 64 + xk[ks]];  \
    _Pragma("unroll") for (int nt = 0; nt < 2; ++nt)                           \
      _Pragma("unroll") for (int ks = 0; ks < 2; ++ks)                         \
        bf[nt][ks] = *(const half8*)&Bs[(RBUF) * 16384 + rB +                  \
                                        ((NH) * 32 + nt * 16) * 64 + xk[ks]];  \
    STAGECODE;                                                                 \
    asm volatile("s_barrier" ::: "memory");                                    \
    __builtin_amdgcn_s_setprio(1);                                             \
    _Pragma("unroll") for (int ks = 0; ks < 2; ++ks)                           \
      _Pragma("unroll") for (int mt = 0; mt < 4; ++mt)                         \
        _Pragma("unroll") for (int nt = 0; nt < 2; ++nt)                       \
          acc[(MH) * 4 + mt][(NH) * 2 + nt] =                                  \
              __builtin_amdgcn_mfma_f32_16x16x32_f16(                          \
                  af[mt][ks], bf[nt][ks], acc[(MH) * 4 + mt][(NH) * 2 + nt],   \
                  0, 0, 0);                                                    \
    __builtin_amdgcn_s_setprio(0);                                             \
    TAILWAIT;                                                                  \
    asm volatile("s_barrier" ::: "memory");                                    \
  } while (0)

#define VM0 asm volatile("s_waitcnt vmcnt(0)" ::: "memory")

  // prologue: tile 0 -> buf0 (8 loads), drain, sync
  SA2(0, 1, 0, 0); SA2(2, 3, 0, 0);
  SB2(0, 1, 0, 0); SB2(2, 3, 0, 0);
  asm volatile("s_waitcnt vmcnt(0)\n\ts_barrier" ::: "memory");

  for (int it = 0; it < 8; ++it) {
    const int t1 = 2 * it + 1;   // staged phases 1-4 -> buf1, read phases 5-8
    const int t2 = 2 * it + 2;   // staged phases 5-8 -> buf0, read next iter
    const bool g2 = (t2 < 16);
    // phases 1-4: read buf0 (tile 2it)
    PHASE(0, 0, 0, SA2(0, 1, 1, t1), );
    PHASE(0, 0, 1, SA2(2, 3, 1, t1), );
    PHASE(0, 1, 0, SB2(0, 1, 1, t1), );
    PHASE(0, 1, 1, SB2(2, 3, 1, t1), VM0);   // t1 fully landed
    // phases 5-8: read buf1 (tile 2it+1)
    PHASE(1, 0, 0, if (g2) SA2(0, 1, 0, t2), );
    PHASE(1, 0, 1, if (g2) SA2(2, 3, 0, t2), );
    PHASE(1, 1, 0, if (g2) SB2(0, 1, 0, t2), );
    PHASE(1, 1, 1, if (g2) SB2(2, 3, 0, t2), VM0);  // t2 landed (or no-op)
  }
#undef VM0
#undef PHASE
#undef SB2
#undef SA2

  // epilogue: C layout col=lr, row=lq*4+r per 16x16 frag; fp16 stores
#pragma unroll
  for (int mt = 0; mt < 8; ++mt)
#pragma unroll
    for (int nt = 0; nt < 4; ++nt) {
      int n = n0 + wn * 64 + nt * 16 + lr;
#pragma unroll
      for (int r = 0; r < 4; ++r) {
        int m = m0 + wm * 128 + mt * 16 + lq * 4 + r;
        outp[(size_t)m * GN + n] = (_Float16)acc[mt][nt][r];
      }
    }
}

// ---------- kernel 4: head — sum KSPLIT fp16 partials, bias, relu, dot W2 ----
__global__ __launch_bounds__(256) void head_kernel(const _Float16* __restrict__ part,
                                                   const float* __restrict__ b1,
                                                   const float* __restrict__ W2,
                                                   const float* __restrict__ b2,
                                                   float* __restrict__ out) {
  const int b = (int)(blockIdx.x * 4 + (threadIdx.x >> 6));
  const int l = (int)(threadIdx.x & 63);
  const size_t stride = (size_t)B_ * GN;   // in halves
  half8 hv = ((const half8*)(part + (size_t)b * GN))[l];
  float a8[8];
#pragma unroll
  for (int j = 0; j < 8; ++j) a8[j] = (float)hv[j];
#pragma unroll
  for (int sp = 1; sp < KSPLIT; ++sp) {
    half8 pv = ((const half8*)(part + sp * stride + (size_t)b * GN))[l];
#pragma unroll
    for (int j = 0; j < 8; ++j) a8[j] += (float)pv[j];
  }
  float4 bv0 = ((const float4*)b1)[2 * l];
  float4 bv1 = ((const float4*)b1)[2 * l + 1];
  float4 wv0 = ((const float4*)W2)[2 * l];
  float4 wv1 = ((const float4*)W2)[2 * l + 1];
  float s = 0.0f;
  s = fmaf(fmaxf(a8[0] + bv0.x, 0.0f), wv0.x, s);
  s = fmaf(fmaxf(a8[1] + bv0.y, 0.0f), wv0.y, s);
  s = fmaf(fmaxf(a8[2] + bv0.z, 0.0f), wv0.z, s);
  s = fmaf(fmaxf(a8[3] + bv0.w, 0.0f), wv0.w, s);
  s = fmaf(fmaxf(a8[4] + bv1.x, 0.0f), wv1.x, s);
  s = fmaf(fmaxf(a8[5] + bv1.y, 0.0f), wv1.y, s);
  s = fmaf(fmaxf(a8[6] + bv1.z, 0.0f), wv1.z, s);
  s = fmaf(fmaxf(a8[7] + bv1.w, 0.0f), wv1.w, s);
#pragma unroll
  for (int off = 32; off >= 1; off >>= 1) s += __shfl_xor(s, off);
  if (l == 0) out[b] = s + b2[0];
}

extern "C" void kernel_launch(void* const* d_in, const int* in_sizes, int n_in,
                              void* d_out, int out_size, void* d_ws, size_t ws_size,
                              hipStream_t stream) {
  const float* batch = (const float*)d_in[0];
  const float* W_ih = (const float*)d_in[1];
  const float* W_hh = (const float*)d_in[2];
  const float* b_ih = (const float*)d_in[3];
  const float* b_hh = (const float*)d_in[4];
  const float* W1 = (const float*)d_in[5];
  const float* b1 = (const float*)d_in[6];
  const float* W2 = (const float*)d_in[7];
  const float* b2 = (const float*)d_in[8];
  float* out = (float*)d_out;

  char* ws = (char*)d_ws;
  _Float16* hs = (_Float16*)ws;                          // 4096*8192*2 = 67108864 B
  _Float16* w1h = (_Float16*)(ws + 67108864);            // 512*8192*2  =  8388608 B
  _Float16* part = (_Float16*)(ws + 67108864 + 8388608); // 8*4096*512*2 = 33554432 B

  cvtw1_kernel<<<4096, 256, 0, stream>>>(W1, (unsigned short*)w1h);
  lstm_kernel<<<256, 512, 0, stream>>>(batch, W_ih, W_hh, b_ih, b_hh, hs);
  gemm_kernel<<<256, 512, 0, stream>>>(hs, w1h, part);
  head_kernel<<<1024, 256, 0, stream>>>(part, b1, W2, b2, out);
}